// Round 2
// baseline (218.759 us; speedup 1.0000x reference)
//
#include <hip/hip_runtime.h>

typedef __attribute__((ext_vector_type(8))) short short8;
typedef __attribute__((ext_vector_type(4))) float f32x4;
typedef unsigned short u16;
typedef unsigned int u32;
typedef unsigned long long u64;

#define XH 114
#define XW 114
#define CINC 64
#define COUT 128
#define OH 112
#define OW 112
#define NB 32
#define KTOT 576   // CIN*9

static __device__ __forceinline__ u16 f2bf(float f) {
    u32 x = __float_as_uint(f);
    u32 r = (x + 0x7fffu + ((x >> 16) & 1u)) >> 16;
    return (u16)r;
}

// ---------------- fast path ----------------

// weights -> bf16, K reordered to (kh,kw,ci):  wbf[o][(kh*3+kw)*64 + ci]
__global__ __launch_bounds__(256) void wcvt_reord(const float* __restrict__ w,
                                                  u16* __restrict__ wbf) {
    int i = blockIdx.x * 256 + threadIdx.x;   // 73728 total, exact
    int o = i / KTOT;
    int rem = i - o * KTOT;
    int khkw = rem >> 6;        // 0..8
    int ci = rem & 63;
    wbf[i] = f2bf(w[(o * CINC + ci) * 9 + khkw]);
}

// x (NCHW f32, padded) -> xb (NHWC bf16): xb[((b*114+h)*114+w)*64 + ci]
__global__ __launch_bounds__(256) void xcvt(const float* __restrict__ x,
                                            u16* __restrict__ xb) {
    __shared__ u16 tile[XW * 68];   // [w][ci] padded stride 68
    const int blk = blockIdx.x;     // 32*114
    const int b = blk / XH;
    const int h = blk - b * XH;
    const int tid = threadIdx.x;

    // phase 1: coalesced read along w, convert, LDS[w*68+ci]
    for (int pass = 0; pass < 29; ++pass) {
        int idx = pass * 256 + tid;          // 0..7295 (114*64)
        if (idx < XW * CINC) {
            int ci = idx / XW;
            int w_ = idx - ci * XW;
            float v = x[((size_t)(b * CINC + ci) * XH + h) * XW + w_];
            tile[w_ * 68 + ci] = f2bf(v);
        }
    }
    __syncthreads();

    // phase 2: write ci-contiguous 16B chunks
    const u64* l64 = (const u64*)tile;
    for (int pass = 0; pass < 4; ++pass) {
        int task = pass * 256 + tid;         // 912 tasks = 114 w * 8 chunks
        if (task < XW * 8) {
            int w_ = task >> 3;
            int c8 = task & 7;
            u64 a0 = l64[17 * w_ + 2 * c8];
            u64 a1 = l64[17 * w_ + 2 * c8 + 1];
            u64* dst = (u64*)(xb + ((size_t)(b * XH + h) * XW + w_) * CINC + c8 * 8);
            dst[0] = a0;
            dst[1] = a1;
        }
    }
}

// implicit-GEMM conv: block = (b,h), 256 thr, waves 2M x 2N, LDS staged once
__global__ __launch_bounds__(256) void conv_nhwc(const u16* __restrict__ xb,
                                                 const u16* __restrict__ wbf,
                                                 const float* __restrict__ bias,
                                                 float* __restrict__ out) {
    __shared__ u16 ldsB[3 * XW * CINC];   // 43776 B: [pix=r*114+w][ci], slot-swizzled
    char* ldsc = (char*)ldsB;

    const int tid = threadIdx.x;
    int bid = blockIdx.x;
    { // bijective XCD swizzle: 3584 = 8*448
        int xcd = bid & 7;
        bid = xcd * 448 + (bid >> 3);
    }
    const int b = bid / OH;
    const int h = bid - b * OH;

    // ---- stage 3 rows (contiguous in xb), swizzle 16B slot by pix&7 ----
    const char* src = (const char*)(xb + (size_t)(b * XH + h) * XW * CINC);
    #pragma unroll
    for (int it = 0; it < 11; ++it) {
        int off = it * 4096 + tid * 16;
        if (off < 3 * XW * CINC * 2) {
            short8 v = *(const short8*)(src + off);
            int pix = off >> 7;
            int slot = (off >> 4) & 7;
            int dst = (off & ~0x70) | ((slot ^ (pix & 7)) << 4);
            *(short8*)(ldsc + dst) = v;
        }
    }
    __syncthreads();

    const int lane = tid & 63;
    const int wv   = tid >> 6;
    const int l16  = lane & 15;
    const int lhi  = lane >> 4;
    const int wm   = wv >> 1;           // cout half: 0/1
    const int wn   = wv & 1;            // n range: 0 -> nf 0..3, 1 -> nf 4..6
    const int nf0  = wn * 4;
    const int nfn  = wn ? 3 : 4;

    f32x4 acc[4][4];
    const f32x4 zero = {0.f, 0.f, 0.f, 0.f};
    #pragma unroll
    for (int i = 0; i < 4; ++i)
        #pragma unroll
        for (int j = 0; j < 4; ++j) acc[i][j] = zero;

    const u16* wrow = wbf + (wm * 64 + l16) * KTOT + lhi * 8;

    #pragma unroll 1
    for (int kh = 0; kh < 3; ++kh) {
        #pragma unroll
        for (int kw = 0; kw < 3; ++kw) {
            #pragma unroll
            for (int ch = 0; ch < 2; ++ch) {
                const int tstep = (kh * 3 + kw) * 2 + ch;
                short8 afrag[4];
                #pragma unroll
                for (int mf = 0; mf < 4; ++mf)
                    afrag[mf] = *(const short8*)(wrow + mf * 16 * KTOT + tstep * 32);

                const int pixbase = kh * XW + kw + l16;
                const int sbase = (ch * 4 + lhi) << 4;
                #pragma unroll
                for (int nf = 0; nf < 4; ++nf) {
                    if (nf >= nfn) break;
                    const int pix = pixbase + (nf0 + nf) * 16;
                    const int baddr = (pix << 7) + (sbase ^ ((pix & 7) << 4));
                    short8 bfrag = *(const short8*)(ldsc + baddr);
                    #pragma unroll
                    for (int mf = 0; mf < 4; ++mf)
                        acc[mf][nf] = __builtin_amdgcn_mfma_f32_16x16x32_bf16(
                            afrag[mf], bfrag, acc[mf][nf], 0, 0, 0);
                }
            }
        }
    }

    // ---- epilogue: C/D col=lane&15, row=(lane>>4)*4+j ----
    float* outb = out + (size_t)b * COUT * (OH * OW) + h * OW;
    #pragma unroll
    for (int mf = 0; mf < 4; ++mf) {
        #pragma unroll
        for (int j = 0; j < 4; ++j) {
            const int o = wm * 64 + mf * 16 + lhi * 4 + j;
            const float bv = bias[o];
            #pragma unroll
            for (int nf = 0; nf < 4; ++nf) {
                if (nf >= nfn) break;
                outb[(size_t)o * (OH * OW) + (nf0 + nf) * 16 + l16] = acc[mf][nf][j] + bv;
            }
        }
    }
}

// ---------------- fallback (R0 kernel, needs only 147456 B ws) ----------------

#define BK 32
#define NSTEP 18
#define LDB 40

__global__ __launch_bounds__(256) void wcvt_ident(const float* __restrict__ w,
                                                  u16* __restrict__ wbf) {
    int i = blockIdx.x * 256 + threadIdx.x;
    if (i < COUT * KTOT) wbf[i] = f2bf(w[i]);
}

__global__ __launch_bounds__(256) void conv_fb(const float* __restrict__ x,
                                               const u16* __restrict__ wbf,
                                               const float* __restrict__ bias,
                                               float* __restrict__ out) {
    __shared__ u16 ldsB[OW * LDB];
    const int tid = threadIdx.x;
    int bid = blockIdx.x;
    { int xcd = bid & 7; bid = xcd * 448 + (bid >> 3); }
    const int b = bid / OH;
    const int h = bid - b * OH;
    const float* xbp = x + (size_t)b * (CINC * XH * XW);
    float* outb = out + (size_t)b * (COUT * OH * OW) + h * OW;
    const int lane = tid & 63, wv = tid >> 6, l16 = lane & 15, lhi = lane >> 4;
    const int m0 = wv * 32;
    const int sk = tid >> 3, sn0 = (tid & 7) * 14;
    f32x4 acc[2][7];
    const f32x4 zero = {0.f, 0.f, 0.f, 0.f};
    #pragma unroll
    for (int i = 0; i < 2; ++i)
        #pragma unroll
        for (int j = 0; j < 7; ++j) acc[i][j] = zero;
    for (int t = 0; t < NSTEP; ++t) {
        const int kg = t * BK + sk;
        const int ci = kg / 9;
        const int r9 = kg - ci * 9;
        const int kh = r9 / 3, kw = r9 - (r9 / 3) * 3;
        const float* src = xbp + ((size_t)ci * XH + (h + kh)) * XW + kw + sn0;
        __syncthreads();
        #pragma unroll
        for (int i = 0; i < 14; ++i) ldsB[(sn0 + i) * LDB + sk] = f2bf(src[i]);
        __syncthreads();
        short8 afrag[2];
        #pragma unroll
        for (int mf = 0; mf < 2; ++mf)
            afrag[mf] = *(const short8*)(wbf + (m0 + mf * 16 + l16) * KTOT + t * BK + lhi * 8);
        #pragma unroll
        for (int nf = 0; nf < 7; ++nf) {
            short8 bfrag = *(const short8*)&ldsB[(nf * 16 + l16) * LDB + lhi * 8];
            acc[0][nf] = __builtin_amdgcn_mfma_f32_16x16x32_bf16(afrag[0], bfrag, acc[0][nf], 0, 0, 0);
            acc[1][nf] = __builtin_amdgcn_mfma_f32_16x16x32_bf16(afrag[1], bfrag, acc[1][nf], 0, 0, 0);
        }
    }
    #pragma unroll
    for (int mf = 0; mf < 2; ++mf)
        #pragma unroll
        for (int j = 0; j < 4; ++j) {
            const int o = m0 + mf * 16 + lhi * 4 + j;
            const float bv = bias[o];
            #pragma unroll
            for (int nf = 0; nf < 7; ++nf)
                outb[(size_t)o * (OH * OW) + nf * 16 + l16] = acc[mf][nf][j] + bv;
        }
}

extern "C" void kernel_launch(void* const* d_in, const int* in_sizes, int n_in,
                              void* d_out, int out_size, void* d_ws, size_t ws_size,
                              hipStream_t stream) {
    const float* x    = (const float*)d_in[0];
    const float* w    = (const float*)d_in[3];
    const float* bias = (const float*)d_in[4];
    float* out = (float*)d_out;

    const size_t WBYTES = (size_t)COUT * KTOT * 2;                 // 147456
    const size_t XBYTES = (size_t)NB * XH * XW * CINC * 2;         // 53231616
    if (ws_size >= WBYTES + XBYTES) {
        u16* wbf = (u16*)d_ws;
        u16* xb  = (u16*)((char*)d_ws + WBYTES);
        wcvt_reord<<<(COUT * KTOT) / 256, 256, 0, stream>>>(w, wbf);
        xcvt<<<NB * XH, 256, 0, stream>>>(x, xb);
        conv_nhwc<<<NB * OH, 256, 0, stream>>>(xb, wbf, bias, out);
    } else {
        u16* wbf = (u16*)d_ws;
        wcvt_ident<<<(COUT * KTOT + 255) / 256, 256, 0, stream>>>(w, wbf);
        conv_fb<<<NB * OH, 256, 0, stream>>>(x, wbf, bias, out);
    }
}

// Round 3
// 146.060 us; speedup vs baseline: 1.4977x; 1.4977x over previous
//
#include <hip/hip_runtime.h>

typedef __attribute__((ext_vector_type(8))) short short8;
typedef __attribute__((ext_vector_type(4))) float f32x4;
typedef unsigned short u16;
typedef unsigned int u32;
typedef unsigned long long u64;

#define XH 114
#define XW 114
#define CINC 64
#define COUT 128
#define OH 112
#define OW 112
#define NB 32
#define KTOT 576   // CIN*9

static __device__ __forceinline__ u16 f2bf(float f) {
    u32 x = __float_as_uint(f);
    u32 r = (x + 0x7fffu + ((x >> 16) & 1u)) >> 16;
    return (u16)r;
}

// ---------------- fast path ----------------

// weights -> bf16, K reordered to (kh,kw,ci):  wbf[o][(kh*3+kw)*64 + ci]
__global__ __launch_bounds__(256) void wcvt_reord(const float* __restrict__ w,
                                                  u16* __restrict__ wbf) {
    int i = blockIdx.x * 256 + threadIdx.x;   // 73728 total, exact
    int o = i / KTOT;
    int rem = i - o * KTOT;
    int khkw = rem >> 6;        // 0..8
    int ci = rem & 63;
    wbf[i] = f2bf(w[(o * CINC + ci) * 9 + khkw]);
}

// x (NCHW f32, padded) -> xb (NHWC bf16): xb[((b*114+h)*114+w)*64 + ci]
__global__ __launch_bounds__(256) void xcvt(const float* __restrict__ x,
                                            u16* __restrict__ xb) {
    __shared__ u16 tile[XW * 68];   // [w][ci] padded stride 68
    const int blk = blockIdx.x;     // 32*114
    const int b = blk / XH;
    const int h = blk - b * XH;
    const int tid = threadIdx.x;

    // phase 1: coalesced read along w, convert, LDS[w*68+ci]
    for (int pass = 0; pass < 29; ++pass) {
        int idx = pass * 256 + tid;          // 0..7295 (114*64)
        if (idx < XW * CINC) {
            int ci = idx / XW;
            int w_ = idx - ci * XW;
            float v = x[((size_t)(b * CINC + ci) * XH + h) * XW + w_];
            tile[w_ * 68 + ci] = f2bf(v);
        }
    }
    __syncthreads();

    // phase 2: write ci-contiguous 16B chunks
    const u64* l64 = (const u64*)tile;
    for (int pass = 0; pass < 4; ++pass) {
        int task = pass * 256 + tid;         // 912 tasks = 114 w * 8 chunks
        if (task < XW * 8) {
            int w_ = task >> 3;
            int c8 = task & 7;
            u64 a0 = l64[17 * w_ + 2 * c8];
            u64 a1 = l64[17 * w_ + 2 * c8 + 1];
            u64* dst = (u64*)(xb + ((size_t)(b * XH + h) * XW + w_) * CINC + c8 * 8);
            dst[0] = a0;
            dst[1] = a1;
        }
    }
}

#define MFMA16(a, b, c) __builtin_amdgcn_mfma_f32_16x16x32_bf16((a), (b), (c), 0, 0, 0)

// implicit-GEMM conv, row-pair blocks: 512 thr = 8 waves (4 cout-groups x 2 rows)
__global__ __launch_bounds__(512, 4) void conv_rp(const u16* __restrict__ xb,
                                                  const u16* __restrict__ wbf,
                                                  const float* __restrict__ bias,
                                                  float* __restrict__ out) {
    __shared__ u16 ldsB[4 * XW * CINC];   // 58368 B: [pix=r*114+w][ci], slot-swizzled
    char* ldsc = (char*)ldsB;

    const int tid = threadIdx.x;
    int bid = blockIdx.x;
    { // bijective XCD swizzle: 1792 = 8*224; each XCD owns 4 whole batches
        int xcd = bid & 7;
        bid = xcd * 224 + (bid >> 3);
    }
    const int b  = bid / 56;
    const int h0 = (bid - b * 56) * 2;

    // ---- stage 4 rows (contiguous in xb), swizzle 16B slot by pix&7 ----
    const char* src = (const char*)(xb + ((size_t)(b * XH + h0) * XW) * CINC);
    #pragma unroll
    for (int it = 0; it < 8; ++it) {
        int off = it * 8192 + tid * 16;
        if (off < 4 * XW * CINC * 2) {
            short8 v = *(const short8*)(src + off);
            int pix = off >> 7;
            int slot = (off >> 4) & 7;
            int dst = (off & ~0x70) | ((slot ^ (pix & 7)) << 4);
            *(short8*)(ldsc + dst) = v;
        }
    }
    __syncthreads();

    const int lane = tid & 63;
    const int wv   = tid >> 6;        // 0..7
    const int l16  = lane & 15;
    const int lhi  = lane >> 4;
    const int wm   = wv & 3;          // cout group: couts [wm*32, wm*32+32)
    const int wn   = wv >> 2;         // row within pair: 0/1

    const u16* wrow0 = wbf + (wm * 32 + l16) * KTOT + lhi * 8;
    const u16* wrow1 = wrow0 + 16 * KTOT;

    f32x4 acc[2][7];
    const f32x4 zero = {0.f, 0.f, 0.f, 0.f};
    #pragma unroll
    for (int i = 0; i < 2; ++i)
        #pragma unroll
        for (int j = 0; j < 7; ++j) acc[i][j] = zero;

    // A-frag software pipeline: tsteps t=0..17, unroll-by-2, 1-ahead prefetch
    short8 aA0 = *(const short8*)(wrow0);
    short8 aA1 = *(const short8*)(wrow1);
    short8 aB0, aB1;

    #pragma unroll 1
    for (int tt = 0; tt < 9; ++tt) {
        const int t0 = 2 * tt;
        // prefetch odd tstep's A
        aB0 = *(const short8*)(wrow0 + (t0 + 1) * 32);
        aB1 = *(const short8*)(wrow1 + (t0 + 1) * 32);

        const int kh = t0 / 6;
        const int kw = (t0 >> 1) % 3;
        const int pix0 = (wn + kh) * XW + kw + l16;
        const int sw = pix0 & 7;

        { // compute t0 (ch=0): slot base lhi
            const int baddr = (pix0 << 7) + ((lhi ^ sw) << 4);
            #pragma unroll
            for (int nf = 0; nf < 7; ++nf) {
                short8 bf = *(const short8*)(ldsc + baddr + nf * 2048);
                acc[0][nf] = MFMA16(aA0, bf, acc[0][nf]);
                acc[1][nf] = MFMA16(aA1, bf, acc[1][nf]);
            }
        }
        // prefetch next even tstep's A
        if (tt < 8) {
            aA0 = *(const short8*)(wrow0 + (t0 + 2) * 32);
            aA1 = *(const short8*)(wrow1 + (t0 + 2) * 32);
        }
        { // compute t1 = t0+1 (ch=1): slot base 4+lhi; same kh,kw
            const int baddr = (pix0 << 7) + (((4 + lhi) ^ sw) << 4);
            #pragma unroll
            for (int nf = 0; nf < 7; ++nf) {
                short8 bf = *(const short8*)(ldsc + baddr + nf * 2048);
                acc[0][nf] = MFMA16(aB0, bf, acc[0][nf]);
                acc[1][nf] = MFMA16(aB1, bf, acc[1][nf]);
            }
        }
    }

    // ---- epilogue: C/D col=lane&15, row=(lane>>4)*4+j ----
    float* outb = out + (size_t)b * COUT * (OH * OW) + (h0 + wn) * OW;
    #pragma unroll
    for (int mf = 0; mf < 2; ++mf) {
        #pragma unroll
        for (int j = 0; j < 4; ++j) {
            const int o = wm * 32 + mf * 16 + lhi * 4 + j;
            const float bv = bias[o];
            #pragma unroll
            for (int nf = 0; nf < 7; ++nf) {
                outb[(size_t)o * (OH * OW) + nf * 16 + l16] = acc[mf][nf][j] + bv;
            }
        }
    }
}

// ---------------- fallback (R0 kernel, needs only 147456 B ws) ----------------

#define BK 32
#define NSTEP 18
#define LDB 40

__global__ __launch_bounds__(256) void wcvt_ident(const float* __restrict__ w,
                                                  u16* __restrict__ wbf) {
    int i = blockIdx.x * 256 + threadIdx.x;
    if (i < COUT * KTOT) wbf[i] = f2bf(w[i]);
}

__global__ __launch_bounds__(256) void conv_fb(const float* __restrict__ x,
                                               const u16* __restrict__ wbf,
                                               const float* __restrict__ bias,
                                               float* __restrict__ out) {
    __shared__ u16 ldsB[OW * LDB];
    const int tid = threadIdx.x;
    int bid = blockIdx.x;
    { int xcd = bid & 7; bid = xcd * 448 + (bid >> 3); }
    const int b = bid / OH;
    const int h = bid - b * OH;
    const float* xbp = x + (size_t)b * (CINC * XH * XW);
    float* outb = out + (size_t)b * (COUT * OH * OW) + h * OW;
    const int lane = tid & 63, wv = tid >> 6, l16 = lane & 15, lhi = lane >> 4;
    const int m0 = wv * 32;
    const int sk = tid >> 3, sn0 = (tid & 7) * 14;
    f32x4 acc[2][7];
    const f32x4 zero = {0.f, 0.f, 0.f, 0.f};
    #pragma unroll
    for (int i = 0; i < 2; ++i)
        #pragma unroll
        for (int j = 0; j < 7; ++j) acc[i][j] = zero;
    for (int t = 0; t < NSTEP; ++t) {
        const int kg = t * BK + sk;
        const int ci = kg / 9;
        const int r9 = kg - ci * 9;
        const int kh = r9 / 3, kw = r9 - (r9 / 3) * 3;
        const float* src = xbp + ((size_t)ci * XH + (h + kh)) * XW + kw + sn0;
        __syncthreads();
        #pragma unroll
        for (int i = 0; i < 14; ++i) ldsB[(sn0 + i) * LDB + sk] = f2bf(src[i]);
        __syncthreads();
        short8 afrag[2];
        #pragma unroll
        for (int mf = 0; mf < 2; ++mf)
            afrag[mf] = *(const short8*)(wbf + (m0 + mf * 16 + l16) * KTOT + t * BK + lhi * 8);
        #pragma unroll
        for (int nf = 0; nf < 7; ++nf) {
            short8 bfrag = *(const short8*)&ldsB[(nf * 16 + l16) * LDB + lhi * 8];
            acc[0][nf] = MFMA16(afrag[0], bfrag, acc[0][nf]);
            acc[1][nf] = MFMA16(afrag[1], bfrag, acc[1][nf]);
        }
    }
    #pragma unroll
    for (int mf = 0; mf < 2; ++mf)
        #pragma unroll
        for (int j = 0; j < 4; ++j) {
            const int o = m0 + mf * 16 + lhi * 4 + j;
            const float bv = bias[o];
            #pragma unroll
            for (int nf = 0; nf < 7; ++nf)
                outb[(size_t)o * (OH * OW) + nf * 16 + l16] = acc[mf][nf][j] + bv;
        }
}

extern "C" void kernel_launch(void* const* d_in, const int* in_sizes, int n_in,
                              void* d_out, int out_size, void* d_ws, size_t ws_size,
                              hipStream_t stream) {
    const float* x    = (const float*)d_in[0];
    const float* w    = (const float*)d_in[3];
    const float* bias = (const float*)d_in[4];
    float* out = (float*)d_out;

    const size_t WBYTES = (size_t)COUT * KTOT * 2;                 // 147456
    const size_t XBYTES = (size_t)NB * XH * XW * CINC * 2;         // 53231616
    if (ws_size >= WBYTES + XBYTES) {
        u16* wbf = (u16*)d_ws;
        u16* xb  = (u16*)((char*)d_ws + WBYTES);
        wcvt_reord<<<(COUT * KTOT) / 256, 256, 0, stream>>>(w, wbf);
        xcvt<<<NB * XH, 256, 0, stream>>>(x, xb);
        conv_rp<<<NB * 56, 512, 0, stream>>>(xb, wbf, bias, out);
    } else {
        u16* wbf = (u16*)d_ws;
        wcvt_ident<<<(COUT * KTOT + 255) / 256, 256, 0, stream>>>(w, wbf);
        conv_fb<<<NB * OH, 256, 0, stream>>>(x, wbf, bias, out);
    }
}